// Round 3
// baseline (907.546 us; speedup 1.0000x reference)
//
#include <hip/hip_runtime.h>

#define N_NODES 50000
#define IN_DIM 512
#define HIDDEN 64
#define OUT_DIM 47

union F4 { float4 v; float f[4]; };

// ---------------------------------------------------------------------------
// K1: h0 = relu(x @ embed_w + embed_b)   [50000,512]@[512,64]
// Block = 256 thr = 4 waves. Wave w owns cols [w*16, w*16+16), lane = row.
// Per block: 64 rows. K staged in LDS transposed [k][row] in 64-chunks;
// weights read wave-uniform (L1 broadcast).
// ---------------------------------------------------------------------------
__global__ __launch_bounds__(256) void embed_gemm(
    const float* __restrict__ x, const float* __restrict__ w,
    const float* __restrict__ b, float* __restrict__ h0) {
  __shared__ float xs[64][65];  // [k][row], pad -> conflict-free b32
  int wid = threadIdx.x >> 6;   // col group (16 cols)
  int lane = threadIdx.x & 63;  // row within tile
  int row0 = blockIdx.x * 64;
  int row = row0 + lane;

  float acc[16];
#pragma unroll
  for (int i = 0; i < 16; i++) acc[i] = 0.f;

  int sr = threadIdx.x >> 2;          // staging row 0..63
  int sc = (threadIdx.x & 3) * 16;    // staging k-offset 0..48

  for (int kc = 0; kc < IN_DIM; kc += 64) {
    __syncthreads();
    // stage x[row0+sr][kc+sc .. +16] -> xs[sc+i][sr]
    {
      F4 v[4];
      if (row0 + sr < N_NODES) {
        const float4* s4 = (const float4*)(x + (size_t)(row0 + sr) * IN_DIM + kc + sc);
        v[0].v = s4[0]; v[1].v = s4[1]; v[2].v = s4[2]; v[3].v = s4[3];
      } else {
#pragma unroll
        for (int q = 0; q < 4; q++) v[q].v = make_float4(0.f, 0.f, 0.f, 0.f);
      }
#pragma unroll
      for (int q = 0; q < 4; q++)
#pragma unroll
        for (int i = 0; i < 4; i++) xs[sc + q * 4 + i][sr] = v[q].f[i];
    }
    __syncthreads();

    for (int k = 0; k < 64; k += 4) {
      float hv[4];
#pragma unroll
      for (int u = 0; u < 4; u++) hv[u] = xs[k + u][lane];
#pragma unroll
      for (int u = 0; u < 4; u++) {
        const float* wr = w + (size_t)(kc + k + u) * HIDDEN + wid * 16;
        F4 w0, w1, w2, w3;
        w0.v = *(const float4*)(wr + 0);
        w1.v = *(const float4*)(wr + 4);
        w2.v = *(const float4*)(wr + 8);
        w3.v = *(const float4*)(wr + 12);
        float hs = hv[u];
#pragma unroll
        for (int i = 0; i < 4; i++) {
          acc[0 + i]  += hs * w0.f[i];
          acc[4 + i]  += hs * w1.f[i];
          acc[8 + i]  += hs * w2.f[i];
          acc[12 + i] += hs * w3.f[i];
        }
      }
    }
  }

  if (row < N_NODES) {
    const float* br = b + wid * 16;
#pragma unroll
    for (int q = 0; q < 4; q++) {
      F4 o;
#pragma unroll
      for (int i = 0; i < 4; i++) {
        float v = acc[q * 4 + i] + br[q * 4 + i];
        o.f[i] = v > 0.f ? v : 0.f;
      }
      *(float4*)(h0 + (size_t)row * HIDDEN + wid * 16 + q * 4) = o.v;
    }
  }
}

// ---------------------------------------------------------------------------
// CSR build step 1: histogram of dst
// ---------------------------------------------------------------------------
__global__ __launch_bounds__(256) void count_edges(const int* __restrict__ dst,
                                                   int E, int* __restrict__ cnt) {
  int stride = gridDim.x * blockDim.x;
  for (int e = blockIdx.x * 256 + threadIdx.x; e < E; e += stride)
    atomicAdd(&cnt[dst[e]], 1);
}

// ---------------------------------------------------------------------------
// CSR build step 2: in-place exclusive scan of two 50000-int arrays.
// ---------------------------------------------------------------------------
__global__ __launch_bounds__(1024) void exscan2(int* a0, int n0, int* a1, int n1) {
  int* a = blockIdx.x ? a1 : a0;
  int n = blockIdx.x ? n1 : n0;
  int tid = threadIdx.x;
  int lane = tid & 63;
  int wid = tid >> 6;  // 16 waves

  __shared__ int wsum[16];
  __shared__ int carry_s, tot_s;
  if (tid == 0) carry_s = 0;
  __syncthreads();

  for (int base = 0; base < n; base += 1024) {
    int i = base + tid;
    int v0 = (i < n) ? a[i] : 0;
    int v = v0;
#pragma unroll
    for (int off = 1; off < 64; off <<= 1) {
      int t = __shfl_up(v, off, 64);
      if (lane >= off) v += t;
    }
    if (lane == 63) wsum[wid] = v;
    __syncthreads();
    if (wid == 0 && lane < 16) {
      int s = wsum[lane], sc = s;
#pragma unroll
      for (int off = 1; off < 16; off <<= 1) {
        int t = __shfl_up(sc, off, 16);
        if (lane >= off) sc += t;
      }
      wsum[lane] = sc - s;
      if (lane == 15) tot_s = sc;
    }
    __syncthreads();
    int excl = carry_s + wsum[wid] + (v - v0);
    if (i < n) a[i] = excl;
    __syncthreads();
    if (tid == 0) carry_s += tot_s;
    __syncthreads();
  }
}

// ---------------------------------------------------------------------------
// CSR build step 3: scatter edges into CSR order (cursor becomes end-ptr)
// ---------------------------------------------------------------------------
__global__ __launch_bounds__(256) void scatter_edges(
    const int* __restrict__ src, const int* __restrict__ dst,
    const float* __restrict__ w, int E, int* __restrict__ cursor,
    int2* __restrict__ ew) {
  int stride = gridDim.x * blockDim.x;
  for (int e = blockIdx.x * 256 + threadIdx.x; e < E; e += stride) {
    int d = dst[e];
    int pos = atomicAdd(&cursor[d], 1);
    ew[pos] = make_int2(src[e], __float_as_int(w[e]));
  }
}

// ---------------------------------------------------------------------------
// Gather SpMM + fused ReLU
// ---------------------------------------------------------------------------
template <int F>
__global__ __launch_bounds__(256) void gather_spmm(
    const int* __restrict__ endptr, const int2* __restrict__ ew,
    const float* __restrict__ h, float* __restrict__ out, int ostride,
    int coff) {
  constexpr int CG = F / 4;
  int tid = blockIdx.x * 256 + threadIdx.x;
  int node = tid / CG;
  int cg = tid % CG;
  if (node >= N_NODES) return;
  int s = (node == 0) ? 0 : endptr[node - 1];
  int e = endptr[node];

  float4 acc = {0.f, 0.f, 0.f, 0.f};
#pragma unroll 2
  for (int j = s; j < e; j++) {
    int2 p = ew[j];
    float wt = __int_as_float(p.y);
    F4 hv;
    hv.v = *(const float4*)(h + (size_t)p.x * F + cg * 4);
    acc.x += wt * hv.f[0];
    acc.y += wt * hv.f[1];
    acc.z += wt * hv.f[2];
    acc.w += wt * hv.f[3];
  }
  F4 o;
  o.f[0] = acc.x > 0.f ? acc.x : 0.f;
  o.f[1] = acc.y > 0.f ? acc.y : 0.f;
  o.f[2] = acc.z > 0.f ? acc.z : 0.f;
  o.f[3] = acc.w > 0.f ? acc.w : 0.f;
  *(float4*)(out + (size_t)node * ostride + coff + cg * 4) = o.v;
}

// ---------------------------------------------------------------------------
// Fallback kernels (atomic scatter SpMM + relu)
// ---------------------------------------------------------------------------
template <int F>
__global__ __launch_bounds__(256) void spmm_atomic(
    const int* __restrict__ src, const int* __restrict__ dst,
    const float* __restrict__ w, int E, const float* __restrict__ h,
    int hstride, float* __restrict__ out, int ostride, int coff) {
  long long total = (long long)E * F;
  long long stride = (long long)gridDim.x * blockDim.x;
  for (long long i = (long long)blockIdx.x * blockDim.x + threadIdx.x;
       i < total; i += stride) {
    int e = (int)(i / F);
    int c = (int)(i % F);
    atomicAdd(out + (size_t)dst[e] * ostride + coff + c,
              w[e] * h[(size_t)src[e] * hstride + c]);
  }
}

__global__ __launch_bounds__(256) void relu_k(float* __restrict__ p, int n4) {
  int stride = gridDim.x * blockDim.x;
  for (int i = blockIdx.x * 256 + threadIdx.x; i < n4; i += stride) {
    F4 v;
    v.v = ((const float4*)p)[i];
#pragma unroll
    for (int j = 0; j < 4; j++) v.f[j] = v.f[j] > 0.f ? v.f[j] : 0.f;
    ((float4*)p)[i] = v.v;
  }
}

// ---------------------------------------------------------------------------
// Pad cls_w [448,47] -> wpad [448,48]
// ---------------------------------------------------------------------------
__global__ __launch_bounds__(256) void pad_w(const float* __restrict__ cls_w,
                                             float* __restrict__ wpad) {
  int idx = blockIdx.x * 256 + threadIdx.x;
  if (idx >= 448 * 48) return;
  int k = idx / 48;
  int j = idx % 48;
  wpad[idx] = (j < 47) ? cls_w[k * 47 + j] : 0.f;
}

// ---------------------------------------------------------------------------
// Final GEMM: out = [h0|hA|hB] @ wpad + cls_b    [50000,448]@[448,48->47]
// Block = 256 thr = 4 waves. Wave w owns cols [w*12, w*12+12), lane = row.
// 64 rows/block; 7 k-chunks of 64 staged transposed in LDS; wpad wave-uniform.
// ---------------------------------------------------------------------------
__global__ __launch_bounds__(256) void final_gemm(
    const float* __restrict__ h0, const float* __restrict__ hA,
    const float* __restrict__ hB, const float* __restrict__ wpad,
    const float* __restrict__ bias, float* __restrict__ out) {
  __shared__ float xs[64][65];  // [k][row]
  int wid = threadIdx.x >> 6;   // col group (12 cols)
  int lane = threadIdx.x & 63;  // row
  int row0 = blockIdx.x * 64;
  int row = row0 + lane;

  float acc[12];
#pragma unroll
  for (int i = 0; i < 12; i++) acc[i] = 0.f;

  int sr = threadIdx.x >> 2;
  int sc = (threadIdx.x & 3) * 16;

  // chunk descriptors: base ptr, row stride, col offset within source
  const float* cb[7] = {h0, hA, hA, hB, hB, hB, hB};
  const int cs[7] = {64, 128, 128, 256, 256, 256, 256};
  const int cc[7] = {0, 0, 64, 0, 64, 128, 192};

  for (int ch = 0; ch < 7; ch++) {
    __syncthreads();
    {
      F4 v[4];
      if (row0 + sr < N_NODES) {
        const float4* s4 =
            (const float4*)(cb[ch] + (size_t)(row0 + sr) * cs[ch] + cc[ch] + sc);
        v[0].v = s4[0]; v[1].v = s4[1]; v[2].v = s4[2]; v[3].v = s4[3];
      } else {
#pragma unroll
        for (int q = 0; q < 4; q++) v[q].v = make_float4(0.f, 0.f, 0.f, 0.f);
      }
#pragma unroll
      for (int q = 0; q < 4; q++)
#pragma unroll
        for (int i = 0; i < 4; i++) xs[sc + q * 4 + i][sr] = v[q].f[i];
    }
    __syncthreads();

    int kc = ch * 64;
    for (int k = 0; k < 64; k += 4) {
      float hv[4];
#pragma unroll
      for (int u = 0; u < 4; u++) hv[u] = xs[k + u][lane];
#pragma unroll
      for (int u = 0; u < 4; u++) {
        const float* wr = wpad + (size_t)(kc + k + u) * 48 + wid * 12;
        F4 w0, w1, w2;
        w0.v = *(const float4*)(wr + 0);
        w1.v = *(const float4*)(wr + 4);
        w2.v = *(const float4*)(wr + 8);
        float hs = hv[u];
#pragma unroll
        for (int i = 0; i < 4; i++) {
          acc[0 + i] += hs * w0.f[i];
          acc[4 + i] += hs * w1.f[i];
          acc[8 + i] += hs * w2.f[i];
        }
      }
    }
  }

  if (row < N_NODES) {
#pragma unroll
    for (int i = 0; i < 12; i++) {
      int c = wid * 12 + i;
      if (c < OUT_DIM) out[(size_t)row * OUT_DIM + c] = acc[i] + bias[c];
    }
  }
}

// ---------------------------------------------------------------------------
extern "C" void kernel_launch(void* const* d_in, const int* in_sizes, int n_in,
                              void* d_out, int out_size, void* d_ws,
                              size_t ws_size, hipStream_t stream) {
  const float* x       = (const float*)d_in[0];
  const int*   src1    = (const int*)d_in[1];
  const int*   dst1    = (const int*)d_in[2];
  const float* w1      = (const float*)d_in[3];
  const int*   src2    = (const int*)d_in[4];
  const int*   dst2    = (const int*)d_in[5];
  const float* w2      = (const float*)d_in[6];
  const float* embed_w = (const float*)d_in[7];
  const float* embed_b = (const float*)d_in[8];
  const float* cls_w   = (const float*)d_in[9];
  const float* cls_b   = (const float*)d_in[10];
  int E1 = in_sizes[1];
  int E2 = in_sizes[4];

  float* ws = (float*)d_ws;
  size_t off = 0;
  float* h0 = ws + off;   off += 3200000;   // 50000*64
  float* hA = ws + off;   off += 6400000;   // 50000*128
  float* hB = ws + off;   off += 12800000;  // 50000*256
  float* wpad = ws + off; off += 21504;     // 448*48
  int* cur1 = (int*)(ws + off); off += 50000;
  int* cur2 = (int*)(ws + off); off += 50000;
  int2* ew1 = (int2*)(ws + off); off += (size_t)2 * E1;
  int2* ew2 = (int2*)(ws + off); off += (size_t)2 * E2;
  size_t need_bytes = off * sizeof(float);

  embed_gemm<<<782, 256, 0, stream>>>(x, embed_w, embed_b, h0);
  pad_w<<<(448 * 48 + 255) / 256, 256, 0, stream>>>(cls_w, wpad);

  if (ws_size >= need_bytes) {
    // ---- CSR gather path ----
    hipMemsetAsync(cur1, 0, 2 * 50000 * sizeof(int), stream);
    count_edges<<<2048, 256, 0, stream>>>(dst1, E1, cur1);
    count_edges<<<2048, 256, 0, stream>>>(dst2, E2, cur2);
    exscan2<<<2, 1024, 0, stream>>>(cur1, N_NODES, cur2, N_NODES);
    scatter_edges<<<2048, 256, 0, stream>>>(src1, dst1, w1, E1, cur1, ew1);
    scatter_edges<<<2048, 256, 0, stream>>>(src2, dst2, w2, E2, cur2, ew2);

    gather_spmm<64><<<3125, 256, 0, stream>>>(cur1, ew1, h0, hA, 128, 0);
    gather_spmm<64><<<3125, 256, 0, stream>>>(cur2, ew2, h0, hA, 128, 64);
    gather_spmm<128><<<6250, 256, 0, stream>>>(cur1, ew1, hA, hB, 256, 0);
    gather_spmm<128><<<6250, 256, 0, stream>>>(cur2, ew2, hA, hB, 256, 128);
  } else {
    // ---- fallback: atomic scatter path ----
    hipMemsetAsync(hA, 0, (size_t)(6400000 + 12800000) * sizeof(float), stream);
    spmm_atomic<64><<<2048, 256, 0, stream>>>(src1, dst1, w1, E1, h0, 64, hA, 128, 0);
    spmm_atomic<64><<<2048, 256, 0, stream>>>(src2, dst2, w2, E2, h0, 64, hA, 128, 64);
    relu_k<<<2048, 256, 0, stream>>>(hA, 6400000 / 4);
    spmm_atomic<128><<<2048, 256, 0, stream>>>(src1, dst1, w1, E1, hA, 128, hB, 256, 0);
    spmm_atomic<128><<<2048, 256, 0, stream>>>(src2, dst2, w2, E2, hA, 128, hB, 256, 128);
    relu_k<<<2048, 256, 0, stream>>>(hB, 12800000 / 4);
  }

  final_gemm<<<782, 256, 0, stream>>>(h0, hA, hB, wpad, cls_b, (float*)d_out);
}